// Round 3
// baseline (3166.255 us; speedup 1.0000x reference)
//
#include <hip/hip_runtime.h>

#define HH 512
#define WW 512
#define BB 4
#define SH 64
#define SW 64
#define NPRE 128
#define LAMV 0.24f
#define EPSV 1e-8f
#define SLOT_STRIDE 16   // ints; one slot per 64B to avoid store contention

// ---------------- prep: cv / ch edge weights (unchanged, verified) ----------------
__global__ __launch_bounds__(256) void prep_kernel(
    const float* __restrict__ image, const float* __restrict__ ybic,
    const float* __restrict__ logk,
    float* __restrict__ cv, float* __restrict__ ch)
{
    int idx = blockIdx.x * 256 + threadIdx.x;
    if (idx >= BB * HH * WW) return;
    int x = idx % WW;
    int y = (idx / WW) % HH;
    int b = idx / (WW * HH);

    float K = expf(logk[0]);
    float invK2 = 1.0f / (K * K);

    const float* img = image + (size_t)b * 3 * HH * WW;
    const float* yb  = ybic  + (size_t)b * HH * WW;

    float f0 = img[y * WW + x];
    float f1 = img[HH * WW + y * WW + x];
    float f2 = img[2 * HH * WW + y * WW + x];
    float f3 = yb[y * WW + x];

    if (y < HH - 1) {
        float s = fabsf(img[(y + 1) * WW + x] - f0)
                + fabsf(img[HH * WW + (y + 1) * WW + x] - f1)
                + fabsf(img[2 * HH * WW + (y + 1) * WW + x] - f2)
                + fabsf(yb[(y + 1) * WW + x] - f3);
        s *= 0.25f;
        cv[(size_t)b * (HH - 1) * WW + y * WW + x] = 1.0f / (1.0f + s * s * invK2);
    }
    if (x < WW - 1) {
        float s = fabsf(img[y * WW + x + 1] - f0)
                + fabsf(img[HH * WW + y * WW + x + 1] - f1)
                + fabsf(img[2 * HH * WW + y * WW + x + 1] - f2)
                + fabsf(yb[y * WW + x + 1] - f3);
        s *= 0.25f;
        ch[(size_t)b * HH * (WW - 1) + y * (WW - 1) + x] = 1.0f / (1.0f + s * s * invK2);
    }
}

// halo buffer layout: [parity][edge][b][tileY][tileX][64]; edges 0=Top,1=Bot,2=Lft,3=Rgt
__device__ __forceinline__ float* hbuf(float* halo, int p, int e, int b, int tY, int tX) {
    return halo + ((size_t)(((p * 4 + e) * BB + b) * 64 + tY * 8 + tX)) * 64;
}

__device__ __forceinline__ void grid_barrier(int* slots, int* flag, int wgid, int tid, int gen) {
    // entry sync: all threads' LDS + global edge stores drained (compiler emits
    // s_waitcnt vmcnt(0) lgkmcnt(0) before s_barrier)
    __syncthreads();
    if (tid == 0)
        __hip_atomic_store(&slots[wgid * SLOT_STRIDE], gen, __ATOMIC_RELEASE, __HIP_MEMORY_SCOPE_AGENT);
    if (wgid == 0) {
        // 256 threads poll the 256 slots
        while (__hip_atomic_load(&slots[tid * SLOT_STRIDE], __ATOMIC_ACQUIRE, __HIP_MEMORY_SCOPE_AGENT) < gen)
            __builtin_amdgcn_s_sleep(1);
        __syncthreads();
        if (tid == 0)
            __hip_atomic_store(flag, gen, __ATOMIC_RELEASE, __HIP_MEMORY_SCOPE_AGENT);
    }
    if (tid == 0) {
        while (__hip_atomic_load(flag, __ATOMIC_ACQUIRE, __HIP_MEMORY_SCOPE_AGENT) < gen)
            __builtin_amdgcn_s_sleep(1);
    }
    __syncthreads();
}

// ---------------- persistent kernel: all 128 iterations, state in registers ----------------
// Grid (8,8,4), 256 threads; thread = 4x4 px; WG = 64x64 tile. 256 WGs co-resident
// by capacity (4 waves + 16KB LDS per WG vs 32 waves + 160KB per CU).
__global__ __launch_bounds__(256) void persist_kernel(
    const float* __restrict__ ybic, float* __restrict__ out_img,
    const float* __restrict__ cv, const float* __restrict__ ch,
    const float* __restrict__ src, const float* __restrict__ mask,
    int* __restrict__ bar, float* __restrict__ halo)
{
    const int b = blockIdx.z, tileY = blockIdx.y, tileX = blockIdx.x;
    const int wgid = (b * 8 + tileY) * 8 + tileX;
    const int tid = threadIdx.x;
    const int tx = tid & 15, ty = tid >> 4;
    const int y0 = tileY * 64 + ty * 4, x0 = tileX * 64 + tx * 4;

    int* slots = bar;
    int* flag  = bar + 256 * SLOT_STRIDE;

    // ---- load state into registers ----
    float I[4][4];
    #pragma unroll
    for (int r = 0; r < 4; ++r) {
        float4 t = *(const float4*)(ybic + ((size_t)b * HH + y0 + r) * WW + x0);
        I[r][0] = t.x; I[r][1] = t.y; I[r][2] = t.z; I[r][3] = t.w;
    }
    float cvaL[5][4];   // lambda * cv at interfaces y0-1 .. y0+3
    #pragma unroll
    for (int i = 0; i < 5; ++i) {
        int y = y0 - 1 + i;
        if (y >= 0 && y < HH - 1) {
            float4 t = *(const float4*)(cv + ((size_t)b * (HH - 1) + y) * WW + x0);
            cvaL[i][0] = t.x * LAMV; cvaL[i][1] = t.y * LAMV;
            cvaL[i][2] = t.z * LAMV; cvaL[i][3] = t.w * LAMV;
        } else {
            #pragma unroll
            for (int c = 0; c < 4; ++c) cvaL[i][c] = 0.0f;
        }
    }
    float chaL[4][5];   // lambda * ch at interfaces x0-1 .. x0+3
    #pragma unroll
    for (int r = 0; r < 4; ++r) {
        const float* row = ch + ((size_t)b * HH + y0 + r) * (WW - 1);
        #pragma unroll
        for (int j = 0; j < 5; ++j) {
            int x = x0 - 1 + j;
            chaL[r][j] = ((unsigned)x <= (unsigned)(WW - 2)) ? row[x] * LAMV : 0.0f;
        }
    }
    const size_t sidx = ((size_t)b * SH + (y0 >> 3)) * SW + (x0 >> 3);
    const float sv = src[sidx];
    const bool useR = (mask[sidx] >= 0.5f);

    // LDS edge exchange buffers (intra-WG halo)
    __shared__ float topE[16][16][4];
    __shared__ float botE[16][16][4];
    __shared__ float lftE[16][16][4];
    __shared__ float rgtE[16][16][4];

    #pragma unroll 1
    for (int k = 0; k < NPRE; ++k) {
        const int p = k & 1;
        // ---- publish current edges ----
        #pragma unroll
        for (int c = 0; c < 4; ++c) {
            topE[ty][tx][c] = I[0][c];
            botE[ty][tx][c] = I[3][c];
            lftE[ty][tx][c] = I[c][0];
            rgtE[ty][tx][c] = I[c][3];
        }
        if (ty == 0)
            *(float4*)(hbuf(halo, p, 0, b, tileY, tileX) + tx * 4) =
                make_float4(I[0][0], I[0][1], I[0][2], I[0][3]);
        if (ty == 15)
            *(float4*)(hbuf(halo, p, 1, b, tileY, tileX) + tx * 4) =
                make_float4(I[3][0], I[3][1], I[3][2], I[3][3]);
        if (tx == 0)
            *(float4*)(hbuf(halo, p, 2, b, tileY, tileX) + ty * 4) =
                make_float4(I[0][0], I[1][0], I[2][0], I[3][0]);
        if (tx == 15)
            *(float4*)(hbuf(halo, p, 3, b, tileY, tileX) + ty * 4) =
                make_float4(I[0][3], I[1][3], I[2][3], I[3][3]);

        grid_barrier(slots, flag, wgid, tid, k + 1);

        // ---- gather halos ----
        float up[4], dn[4], lf[4], rg[4];
        if (ty > 0) {
            #pragma unroll
            for (int c = 0; c < 4; ++c) up[c] = botE[ty - 1][tx][c];
        } else if (tileY > 0) {
            float4 t = *(const float4*)(hbuf(halo, p, 1, b, tileY - 1, tileX) + tx * 4);
            up[0] = t.x; up[1] = t.y; up[2] = t.z; up[3] = t.w;
        } else { up[0] = up[1] = up[2] = up[3] = 0.0f; }

        if (ty < 15) {
            #pragma unroll
            for (int c = 0; c < 4; ++c) dn[c] = topE[ty + 1][tx][c];
        } else if (tileY < 7) {
            float4 t = *(const float4*)(hbuf(halo, p, 0, b, tileY + 1, tileX) + tx * 4);
            dn[0] = t.x; dn[1] = t.y; dn[2] = t.z; dn[3] = t.w;
        } else { dn[0] = dn[1] = dn[2] = dn[3] = 0.0f; }

        if (tx > 0) {
            #pragma unroll
            for (int r = 0; r < 4; ++r) lf[r] = rgtE[ty][tx - 1][r];
        } else if (tileX > 0) {
            float4 t = *(const float4*)(hbuf(halo, p, 3, b, tileY, tileX - 1) + ty * 4);
            lf[0] = t.x; lf[1] = t.y; lf[2] = t.z; lf[3] = t.w;
        } else { lf[0] = lf[1] = lf[2] = lf[3] = 0.0f; }

        if (tx < 15) {
            #pragma unroll
            for (int r = 0; r < 4; ++r) rg[r] = lftE[ty][tx + 1][r];
        } else if (tileX < 7) {
            float4 t = *(const float4*)(hbuf(halo, p, 2, b, tileY, tileX + 1) + ty * 4);
            rg[0] = t.x; rg[1] = t.y; rg[2] = t.z; rg[3] = t.w;
        } else { rg[0] = rg[1] = rg[2] = rg[3] = 0.0f; }

        // LDS reads done; next iteration's publish may not overwrite before this point
        __syncthreads();

        // ---- diffuse + block mean + adjust ----
        float nv[4][4];
        float s = 0.0f;
        #pragma unroll
        for (int r = 0; r < 4; ++r) {
            #pragma unroll
            for (int c = 0; c < 4; ++c) {
                const float v = I[r][c];
                const float u = r       ? I[r - 1][c] : up[c];
                const float d = (r < 3) ? I[r + 1][c] : dn[c];
                const float l = c       ? I[r][c - 1] : lf[r];
                const float g = (c < 3) ? I[r][c + 1] : rg[r];
                const float t = cvaL[r + 1][c] * (d - v)
                              - cvaL[r][c]     * (v - u)
                              + chaL[r][c + 1] * (g - v)
                              - chaL[r][c]     * (v - l);
                const float w = v + t;
                nv[r][c] = w;
                s += w;
            }
        }
        // 8x8 block = 2x2 thread group (lanes ^1 and ^16, same wave)
        s += __shfl_xor(s, 1);
        s += __shfl_xor(s, 16);
        const float mean  = s * (1.0f / 64.0f);
        const float ratio = useR ? (sv / (mean + EPSV)) : 1.0f;
        #pragma unroll
        for (int r = 0; r < 4; ++r)
            #pragma unroll
            for (int c = 0; c < 4; ++c) I[r][c] = nv[r][c] * ratio;
    }

    // ---- store final image ----
    #pragma unroll
    for (int r = 0; r < 4; ++r)
        *(float4*)(out_img + ((size_t)b * HH + y0 + r) * WW + x0) =
            make_float4(I[r][0], I[r][1], I[r][2], I[r][3]);
}

extern "C" void kernel_launch(void* const* d_in, const int* in_sizes, int n_in,
                              void* d_out, int out_size, void* d_ws, size_t ws_size,
                              hipStream_t stream) {
    const float* image  = (const float*)d_in[0];
    const float* source = (const float*)d_in[1];
    const float* mask   = (const float*)d_in[2];
    const float* ybic   = (const float*)d_in[3];
    const float* logk   = (const float*)d_in[4];

    float* out_img = (float*)d_out;                          // [B,1,H,W]
    float* out_cv  = out_img + (size_t)BB * HH * WW;         // [B,1,H-1,W]
    float* out_ch  = out_cv + (size_t)BB * (HH - 1) * WW;    // [B,1,H,W-1]

    int*   bar  = (int*)d_ws;                                // 256 slots (64B apart) + flag
    float* halo = (float*)d_ws + 8192;                       // 512 KB halo buffers (after 32KB)

    // zero the barrier region every call (deterministic; graph-capturable memset node)
    hipMemsetAsync(d_ws, 0, 32768, stream);

    int total = BB * HH * WW;
    prep_kernel<<<(total + 255) / 256, 256, 0, stream>>>(image, ybic, logk, out_cv, out_ch);

    dim3 grid(WW / 64, HH / 64, BB);
    persist_kernel<<<grid, 256, 0, stream>>>(ybic, out_img, out_cv, out_ch,
                                             source, mask, bar, halo);
}

// Round 4
// 334.885 us; speedup vs baseline: 9.4548x; 9.4548x over previous
//
#include <hip/hip_runtime.h>

#define HH 512
#define WW 512
#define BB 4
#define SH 64
#define SW 64
#define NPRE 128
#define LAMV 0.24f
#define EPSV 1e-8f
#define FLAG_STRIDE 16   // ints; one flag per 64B line

// ---------------- prep: cv / ch edge weights (unchanged, verified) ----------------
__global__ __launch_bounds__(256) void prep_kernel(
    const float* __restrict__ image, const float* __restrict__ ybic,
    const float* __restrict__ logk,
    float* __restrict__ cv, float* __restrict__ ch)
{
    int idx = blockIdx.x * 256 + threadIdx.x;
    if (idx >= BB * HH * WW) return;
    int x = idx % WW;
    int y = (idx / WW) % HH;
    int b = idx / (WW * HH);

    float K = expf(logk[0]);
    float invK2 = 1.0f / (K * K);

    const float* img = image + (size_t)b * 3 * HH * WW;
    const float* yb  = ybic  + (size_t)b * HH * WW;

    float f0 = img[y * WW + x];
    float f1 = img[HH * WW + y * WW + x];
    float f2 = img[2 * HH * WW + y * WW + x];
    float f3 = yb[y * WW + x];

    if (y < HH - 1) {
        float s = fabsf(img[(y + 1) * WW + x] - f0)
                + fabsf(img[HH * WW + (y + 1) * WW + x] - f1)
                + fabsf(img[2 * HH * WW + (y + 1) * WW + x] - f2)
                + fabsf(yb[(y + 1) * WW + x] - f3);
        s *= 0.25f;
        cv[(size_t)b * (HH - 1) * WW + y * WW + x] = 1.0f / (1.0f + s * s * invK2);
    }
    if (x < WW - 1) {
        float s = fabsf(img[y * WW + x + 1] - f0)
                + fabsf(img[HH * WW + y * WW + x + 1] - f1)
                + fabsf(img[2 * HH * WW + y * WW + x + 1] - f2)
                + fabsf(yb[y * WW + x + 1] - f3);
        s *= 0.25f;
        ch[(size_t)b * HH * (WW - 1) + y * (WW - 1) + x] = 1.0f / (1.0f + s * s * invK2);
    }
}

// halo layout: [parity][edge][b][tileY][tileX][64]; edges 0=Top,1=Bot,2=Lft,3=Rgt
__device__ __forceinline__ float* hbuf(float* halo, int p, int e, int b, int tY, int tX) {
    return halo + ((size_t)(((p * 4 + e) * BB + b) * 64 + tY * 8 + tX)) * 64;
}

// 8B relaxed agent-scope atomics: sc0|sc1 -> served at the coherent IF$ point,
// never resident in (incoherent) L1/L2; no cache-maintenance ops in the loop.
__device__ __forceinline__ void st8(float* p, float a, float b) {
    unsigned long long v = __builtin_bit_cast(unsigned long long, make_float2(a, b));
    __hip_atomic_store((unsigned long long*)p, v, __ATOMIC_RELAXED, __HIP_MEMORY_SCOPE_AGENT);
}
__device__ __forceinline__ float2 ld8(float* p) {
    unsigned long long v =
        __hip_atomic_load((unsigned long long*)p, __ATOMIC_RELAXED, __HIP_MEMORY_SCOPE_AGENT);
    return __builtin_bit_cast(float2, v);
}
__device__ __forceinline__ void wait_flag(int* f, int gen) {
    while (__hip_atomic_load(f, __ATOMIC_RELAXED, __HIP_MEMORY_SCOPE_AGENT) < gen)
        __builtin_amdgcn_s_sleep(1);
}

// ---------------- persistent kernel: 128 iterations, neighbor handshakes ----------------
// Grid (8,8,4), 256 threads; thread = 4x4 px; WG = 64x64 tile; all 256 WGs resident.
__global__ __launch_bounds__(256) void persist_kernel(
    const float* __restrict__ ybic, float* __restrict__ out_img,
    const float* __restrict__ cv, const float* __restrict__ ch,
    const float* __restrict__ src, const float* __restrict__ mask,
    int* __restrict__ flags, float* __restrict__ halo)
{
    const int b = blockIdx.z, tileY = blockIdx.y, tileX = blockIdx.x;
    const int wgid = (b * 8 + tileY) * 8 + tileX;
    const int tid = threadIdx.x;
    const int tx = tid & 15, ty = tid >> 4;
    const int y0 = tileY * 64 + ty * 4, x0 = tileX * 64 + tx * 4;

    // ---- load state into registers ----
    float I[4][4];
    #pragma unroll
    for (int r = 0; r < 4; ++r) {
        float4 t = *(const float4*)(ybic + ((size_t)b * HH + y0 + r) * WW + x0);
        I[r][0] = t.x; I[r][1] = t.y; I[r][2] = t.z; I[r][3] = t.w;
    }
    float cvaL[5][4];   // lambda * cv at interfaces y0-1 .. y0+3
    #pragma unroll
    for (int i = 0; i < 5; ++i) {
        int y = y0 - 1 + i;
        if (y >= 0 && y < HH - 1) {
            float4 t = *(const float4*)(cv + ((size_t)b * (HH - 1) + y) * WW + x0);
            cvaL[i][0] = t.x * LAMV; cvaL[i][1] = t.y * LAMV;
            cvaL[i][2] = t.z * LAMV; cvaL[i][3] = t.w * LAMV;
        } else {
            #pragma unroll
            for (int c = 0; c < 4; ++c) cvaL[i][c] = 0.0f;
        }
    }
    float chaL[4][5];   // lambda * ch at interfaces x0-1 .. x0+3
    #pragma unroll
    for (int r = 0; r < 4; ++r) {
        const float* row = ch + ((size_t)b * HH + y0 + r) * (WW - 1);
        #pragma unroll
        for (int j = 0; j < 5; ++j) {
            int x = x0 - 1 + j;
            chaL[r][j] = ((unsigned)x <= (unsigned)(WW - 2)) ? row[x] * LAMV : 0.0f;
        }
    }
    const size_t sidx = ((size_t)b * SH + (y0 >> 3)) * SW + (x0 >> 3);
    const float sv = src[sidx];
    const bool useR = (mask[sidx] >= 0.5f);

    // LDS edge exchange (intra-WG halo)
    __shared__ float topE[16][16][4];
    __shared__ float botE[16][16][4];
    __shared__ float lftE[16][16][4];
    __shared__ float rgtE[16][16][4];

    int* myFlag = &flags[wgid * FLAG_STRIDE];

    #pragma unroll 1
    for (int k = 0; k < NPRE; ++k) {
        const int p = k & 1;
        const int gen = k + 1;

        // ---- publish edges: LDS (intra-WG) + IF$ atomics (inter-WG) ----
        #pragma unroll
        for (int c = 0; c < 4; ++c) {
            topE[ty][tx][c] = I[0][c];
            botE[ty][tx][c] = I[3][c];
            lftE[ty][tx][c] = I[c][0];
            rgtE[ty][tx][c] = I[c][3];
        }
        if (ty == 0) {
            float* e = hbuf(halo, p, 0, b, tileY, tileX) + tx * 4;
            st8(e, I[0][0], I[0][1]); st8(e + 2, I[0][2], I[0][3]);
        }
        if (ty == 15) {
            float* e = hbuf(halo, p, 1, b, tileY, tileX) + tx * 4;
            st8(e, I[3][0], I[3][1]); st8(e + 2, I[3][2], I[3][3]);
        }
        if (tx == 0) {
            float* e = hbuf(halo, p, 2, b, tileY, tileX) + ty * 4;
            st8(e, I[0][0], I[1][0]); st8(e + 2, I[2][0], I[3][0]);
        }
        if (tx == 15) {
            float* e = hbuf(halo, p, 3, b, tileY, tileX) + ty * 4;
            st8(e, I[0][3], I[1][3]); st8(e + 2, I[2][3], I[3][3]);
        }
        // compiler emits s_waitcnt vmcnt(0) lgkmcnt(0) before s_barrier:
        // all waves' edge stores are at the coherence point after this.
        __syncthreads();
        if (tid == 0)
            __hip_atomic_store(myFlag, gen, __ATOMIC_RELAXED, __HIP_MEMORY_SCOPE_AGENT);
        asm volatile("" ::: "memory");

        // ---- gather halos (boundary threads poll their neighbor's flag) ----
        float up[4], dn[4], lf[4], rg[4];
        if (ty > 0) {
            #pragma unroll
            for (int c = 0; c < 4; ++c) up[c] = botE[ty - 1][tx][c];
        } else if (tileY > 0) {
            wait_flag(&flags[(wgid - 8) * FLAG_STRIDE], gen);
            float* e = hbuf(halo, p, 1, b, tileY - 1, tileX) + tx * 4;
            float2 a = ld8(e), c2 = ld8(e + 2);
            up[0] = a.x; up[1] = a.y; up[2] = c2.x; up[3] = c2.y;
        } else { up[0] = up[1] = up[2] = up[3] = 0.0f; }

        if (ty < 15) {
            #pragma unroll
            for (int c = 0; c < 4; ++c) dn[c] = topE[ty + 1][tx][c];
        } else if (tileY < 7) {
            wait_flag(&flags[(wgid + 8) * FLAG_STRIDE], gen);
            float* e = hbuf(halo, p, 0, b, tileY + 1, tileX) + tx * 4;
            float2 a = ld8(e), c2 = ld8(e + 2);
            dn[0] = a.x; dn[1] = a.y; dn[2] = c2.x; dn[3] = c2.y;
        } else { dn[0] = dn[1] = dn[2] = dn[3] = 0.0f; }

        if (tx > 0) {
            #pragma unroll
            for (int r = 0; r < 4; ++r) lf[r] = rgtE[ty][tx - 1][r];
        } else if (tileX > 0) {
            wait_flag(&flags[(wgid - 1) * FLAG_STRIDE], gen);
            float* e = hbuf(halo, p, 3, b, tileY, tileX - 1) + ty * 4;
            float2 a = ld8(e), c2 = ld8(e + 2);
            lf[0] = a.x; lf[1] = a.y; lf[2] = c2.x; lf[3] = c2.y;
        } else { lf[0] = lf[1] = lf[2] = lf[3] = 0.0f; }

        if (tx < 15) {
            #pragma unroll
            for (int r = 0; r < 4; ++r) rg[r] = lftE[ty][tx + 1][r];
        } else if (tileX < 7) {
            wait_flag(&flags[(wgid + 1) * FLAG_STRIDE], gen);
            float* e = hbuf(halo, p, 2, b, tileY, tileX + 1) + ty * 4;
            float2 a = ld8(e), c2 = ld8(e + 2);
            rg[0] = a.x; rg[1] = a.y; rg[2] = c2.x; rg[3] = c2.y;
        } else { rg[0] = rg[1] = rg[2] = rg[3] = 0.0f; }

        asm volatile("" ::: "memory");
        // LDS reads done; next iteration's publish may not overwrite before this point
        __syncthreads();

        // ---- diffuse + block mean + adjust ----
        float nv[4][4];
        float s = 0.0f;
        #pragma unroll
        for (int r = 0; r < 4; ++r) {
            #pragma unroll
            for (int c = 0; c < 4; ++c) {
                const float v = I[r][c];
                const float u = r       ? I[r - 1][c] : up[c];
                const float d = (r < 3) ? I[r + 1][c] : dn[c];
                const float l = c       ? I[r][c - 1] : lf[r];
                const float g = (c < 3) ? I[r][c + 1] : rg[r];
                const float t = cvaL[r + 1][c] * (d - v)
                              - cvaL[r][c]     * (v - u)
                              + chaL[r][c + 1] * (g - v)
                              - chaL[r][c]     * (v - l);
                const float w = v + t;
                nv[r][c] = w;
                s += w;
            }
        }
        // 8x8 block = 2x2 thread group (lanes ^1 and ^16, same wave)
        s += __shfl_xor(s, 1);
        s += __shfl_xor(s, 16);
        const float mean  = s * (1.0f / 64.0f);
        const float ratio = useR ? (sv / (mean + EPSV)) : 1.0f;
        #pragma unroll
        for (int r = 0; r < 4; ++r)
            #pragma unroll
            for (int c = 0; c < 4; ++c) I[r][c] = nv[r][c] * ratio;
    }

    // ---- store final image ----
    #pragma unroll
    for (int r = 0; r < 4; ++r)
        *(float4*)(out_img + ((size_t)b * HH + y0 + r) * WW + x0) =
            make_float4(I[r][0], I[r][1], I[r][2], I[r][3]);
}

extern "C" void kernel_launch(void* const* d_in, const int* in_sizes, int n_in,
                              void* d_out, int out_size, void* d_ws, size_t ws_size,
                              hipStream_t stream) {
    const float* image  = (const float*)d_in[0];
    const float* source = (const float*)d_in[1];
    const float* mask   = (const float*)d_in[2];
    const float* ybic   = (const float*)d_in[3];
    const float* logk   = (const float*)d_in[4];

    float* out_img = (float*)d_out;                          // [B,1,H,W]
    float* out_cv  = out_img + (size_t)BB * HH * WW;         // [B,1,H-1,W]
    float* out_ch  = out_cv + (size_t)BB * (HH - 1) * WW;    // [B,1,H,W-1]

    int*   flags = (int*)d_ws;                               // 256 flags, 64B apart (16KB)
    float* halo  = (float*)d_ws + 8192;                      // 512KB halo after 32KB

    // reset flags every call (graph-capturable async memset)
    hipMemsetAsync(d_ws, 0, 16384, stream);

    int total = BB * HH * WW;
    prep_kernel<<<(total + 255) / 256, 256, 0, stream>>>(image, ybic, logk, out_cv, out_ch);

    dim3 grid(WW / 64, HH / 64, BB);
    persist_kernel<<<grid, 256, 0, stream>>>(ybic, out_img, out_cv, out_ch,
                                             source, mask, flags, halo);
}